// Round 6
// baseline (83.949 us; speedup 1.0000x reference)
//
#include <hip/hip_runtime.h>
#include <math.h>

#define TOPK 50
#define NCH 225
#define NBINS 16384
#define BPT 32              // bins per thread chunk (16384 / 512)
#define PADC 33             // padded chunk stride
#define CAP 256
#define NT 512
#define NW 8
#define MAXIT 4             // ceil(6400 / 2048)

// monotone float->uint key: preserves ordering, larger float -> larger key
__device__ __forceinline__ unsigned int f2key(float f) {
    unsigned int u = __float_as_uint(f);
    return (u & 0x80000000u) ? ~u : (u | 0x80000000u);
}
__device__ __forceinline__ float key2f(unsigned int k) {
    unsigned int u = (k & 0x80000000u) ? (k ^ 0x80000000u) : ~k;
    return __uint_as_float(u);
}
__device__ __forceinline__ int pbin(unsigned int bin) {
    return (int)((bin >> 5) * PADC + (bin & 31u));
}

struct Args {
    const float* conf[3];
    const float* obj[3];
    const float* act[3];
    const float* rel[3];
    const float* intp[3];
    const float* reg[3];
    unsigned int* ctr;      // 96 counters (zeroed by memset before launch)
    uint2* cand;            // 96 groups * 4 chunks * 50
    float* out;
};

__global__ __launch_bounds__(NT, 4)
void yowo_fused_kernel(Args a) {
    __shared__ unsigned int s_hist[NT * PADC];     // 66 KB, pad-33 layout
    __shared__ unsigned int s_wtot[NW];
    __shared__ unsigned int s_woff[NW];
    __shared__ unsigned int s_ck[CAP];
    __shared__ unsigned int s_ci[CAP];
    __shared__ unsigned int s_selKey[TOPK];
    __shared__ unsigned int s_selIdx[TOPK];
    __shared__ unsigned int s_cnt;
    __shared__ unsigned int s_bin, s_cntGe;
    __shared__ unsigned long long s_wred[NW];
    __shared__ unsigned long long s_prev;

    const int tid  = threadIdx.x;
    const int wid  = tid >> 6;
    const int lane = tid & 63;
    const int grp  = blockIdx.x >> 2;   // 0..95 = lvl*32 + b
    const int sub  = blockIdx.x & 3;
    const int lvl  = grp >> 5;
    const int b    = grp & 31;

    const int M      = (lvl == 0) ? 25600 : (lvl == 1) ? 6400 : 1600;
    const int Mc     = M >> 2;                       // chunk size: 6400/1600/400
    const int stride = 8 << lvl;
    const int n      = 1280 / stride;
    const int base   = sub * Mc;
    const float* confp = a.conf[lvl] + (size_t)b * M + base;

    // ---------------- Phase 1: exact top-50 of this chunk ----------------
    {
        const int zb = tid * PADC;
        #pragma unroll
        for (int j = 0; j < PADC; ++j) s_hist[zb + j] = 0u;
    }
    __syncthreads();

    uint4 kk[MAXIT];
    #pragma unroll
    for (int it = 0; it < MAXIT; ++it) {
        const int m = tid * 4 + it * (NT * 4);
        if (m < Mc) {
            float4 c4 = *(const float4*)(confp + m);
            uint4 k4 = make_uint4(f2key(c4.x), f2key(c4.y), f2key(c4.z), f2key(c4.w));
            kk[it] = k4;
            atomicAdd(&s_hist[pbin(k4.x >> 18)], 1u);
            atomicAdd(&s_hist[pbin(k4.y >> 18)], 1u);
            atomicAdd(&s_hist[pbin(k4.z >> 18)], 1u);
            atomicAdd(&s_hist[pbin(k4.w >> 18)], 1u);
        }
    }
    __syncthreads();

    // chunk totals + hierarchical suffix scan
    const int pb = tid * PADC;
    unsigned int ct = 0u;
    #pragma unroll
    for (int j = 0; j < BPT; ++j) ct += s_hist[pb + j];
    unsigned int sfx = ct;
    #pragma unroll
    for (int off = 1; off < 64; off <<= 1) {
        unsigned int v = __shfl_down(sfx, off, 64);
        if (lane + off < 64) sfx += v;
    }
    if (lane == 0) s_wtot[wid] = sfx;
    __syncthreads();
    if (tid < NW) {
        unsigned int o = 0u;
        for (int j = tid + 1; j < NW; ++j) o += s_wtot[j];
        s_woff[tid] = o;
    }
    __syncthreads();
    const unsigned int S_incl = sfx + s_woff[wid];
    const unsigned int right  = S_incl - ct;

    if (right < TOPK && S_incl >= TOPK) {
        unsigned int cge = right;
        #pragma unroll
        for (int j = BPT - 1; j >= 0; --j) {
            cge += s_hist[pb + j];
            if (cge >= TOPK) { s_bin = (unsigned int)(tid * BPT + j); s_cntGe = cge; break; }
        }
    }
    __syncthreads();

    const unsigned int cntGe = s_cntGe;
    const unsigned int thr   = s_bin << 18;

    if (cntGe <= CAP) {
        if (tid == 0) s_cnt = 0u;
        __syncthreads();
        #pragma unroll
        for (int it = 0; it < MAXIT; ++it) {
            const int m = tid * 4 + it * (NT * 4);
            if (m < Mc) {
                const uint4 k4 = kk[it];
                #pragma unroll
                for (int j = 0; j < 4; ++j) {
                    const unsigned int k = (j == 0) ? k4.x : (j == 1) ? k4.y
                                         : (j == 2) ? k4.z : k4.w;
                    if (k >= thr) {
                        unsigned int pos = atomicAdd(&s_cnt, 1u);
                        if (pos < CAP) {
                            s_ck[pos] = k;
                            s_ci[pos] = (unsigned int)(base + m + j);   // global idx
                        }
                    }
                }
            }
        }
        __syncthreads();
        const unsigned int cnt = s_cnt;
        if (tid < (int)cnt) {
            const unsigned long long p =
                ((unsigned long long)s_ck[tid] << 32) | (unsigned int)(~s_ci[tid]);
            int rank = 0;
            for (unsigned int j = 0; j < cnt; ++j) {
                const unsigned long long q =
                    ((unsigned long long)s_ck[j] << 32) | (unsigned int)(~s_ci[j]);
                rank += (q > p) ? 1 : 0;
            }
            if (rank < TOPK) { s_selKey[rank] = s_ck[tid]; s_selIdx[rank] = s_ci[tid]; }
        }
        __syncthreads();
    } else {
        // exact fallback (massive key ties; never expected): 50 descending max passes
        unsigned long long prev = 0xFFFFFFFFFFFFFFFFull;
        for (int i = 0; i < TOPK; ++i) {
            unsigned long long p = 0ull;
            #pragma unroll
            for (int it = 0; it < MAXIT; ++it) {
                const int m = tid * 4 + it * (NT * 4);
                if (m < Mc) {
                    const uint4 k4 = kk[it];
                    #pragma unroll
                    for (int j = 0; j < 4; ++j) {
                        const unsigned int k = (j == 0) ? k4.x : (j == 1) ? k4.y
                                             : (j == 2) ? k4.z : k4.w;
                        const unsigned long long pk =
                            ((unsigned long long)k << 32) |
                            (unsigned int)(~(unsigned int)(base + m + j));
                        if (pk < prev && pk > p) p = pk;
                    }
                }
            }
            #pragma unroll
            for (int off = 32; off > 0; off >>= 1) {
                unsigned long long q = __shfl_xor(p, off, 64);
                if (q > p) p = q;
            }
            if (lane == 0) s_wred[wid] = p;
            __syncthreads();
            if (tid == 0) {
                unsigned long long w = s_wred[0];
                #pragma unroll
                for (int j = 1; j < NW; ++j) if (s_wred[j] > w) w = s_wred[j];
                s_prev = w;
                s_selKey[i] = (unsigned int)(w >> 32);
                s_selIdx[i] = ~(unsigned int)w;
            }
            __syncthreads();
            prev = s_prev;
            __syncthreads();
        }
    }

    // publish chunk top-50
    if (tid < TOPK)
        a.cand[((size_t)grp * 4 + sub) * TOPK + tid] =
            make_uint2(s_selKey[tid], s_selIdx[tid]);
    __threadfence();                 // device-scope release of the stores above
    __syncthreads();
    if (tid == 0)
        __hip_atomic_fetch_add(&a.ctr[grp], 1u, __ATOMIC_RELEASE,
                               __HIP_MEMORY_SCOPE_AGENT);

    // ---------------- Phase 2: wait for this group's 4 chunks ----------------
    if (tid == 0) {
        long iters = 0;
        while (__hip_atomic_load(&a.ctr[grp], __ATOMIC_ACQUIRE,
                                 __HIP_MEMORY_SCOPE_AGENT) < 4u) {
            __builtin_amdgcn_s_sleep(2);
            if (++iters > 200000000L) break;   // safety valve (never expected)
        }
    }
    __syncthreads();

    // merge the group's 200 candidates (L2-hot), exact lax.top_k semantics
    const uint2* cp = a.cand + (size_t)grp * 4 * TOPK;
    if (tid < 4 * TOPK) {
        uint2 e = cp[tid];
        s_ck[tid] = e.x;
        s_ci[tid] = e.y;
    }
    __syncthreads();
    if (tid < 4 * TOPK) {
        const unsigned long long p =
            ((unsigned long long)s_ck[tid] << 32) | (unsigned int)(~s_ci[tid]);
        int rank = 0;
        for (int j = 0; j < 4 * TOPK; ++j) {
            const unsigned long long q =
                ((unsigned long long)s_ck[j] << 32) | (unsigned int)(~s_ci[j]);
            rank += (q > p) ? 1 : 0;
        }
        if (rank < TOPK) { s_selKey[rank] = s_ck[tid]; s_selIdx[rank] = s_ci[tid]; }
    }
    __syncthreads();

    // ---------------- Phase 3: write this block's rows (k % 4 == sub) ----------------
    for (int k = sub + 4 * wid; k < TOPK; k += 4 * NW) {
        const unsigned int idx = s_selIdx[k];
        const float logit = key2f(s_selKey[k]);
        const float sc   = 1.0f / (1.0f + expf(-logit));
        const float keep = (sc > 0.05f) ? 1.0f : 0.0f;

        float* orow = a.out + ((size_t)b * 150 + (size_t)lvl * TOPK + k) * NCH;
        const size_t rbase = (size_t)b * M + idx;

        // obj softmax over 36 classes
        float e = 0.0f;
        if (lane < 36) e = expf(a.obj[lvl][rbase * 36 + lane]);
        float s = e;
        #pragma unroll
        for (int off = 32; off > 0; off >>= 1) s += __shfl_xor(s, off, 64);
        if (lane < 36) orow[6 + lane] = keep * (e / s);

        // act sigmoid (157)
        for (int c = lane; c < 157; c += 64) {
            float x = a.act[lvl][rbase * 157 + c];
            orow[42 + c] = keep / (1.0f + expf(-x));
        }
        // rel sigmoid (26)
        if (lane < 26) {
            float x = a.rel[lvl][rbase * 26 + lane];
            orow[199 + lane] = keep / (1.0f + expf(-x));
        }
        // conf, inter, box
        if (lane == 0) {
            orow[4] = keep * sc;
            float xi = a.intp[lvl][rbase];
            orow[5] = keep / (1.0f + expf(-xi));
            const float r0 = a.reg[lvl][rbase * 4 + 0];
            const float r1 = a.reg[lvl][rbase * 4 + 1];
            const float r2 = a.reg[lvl][rbase * 4 + 2];
            const float r3 = a.reg[lvl][rbase * 4 + 3];
            const int yy = (int)idx / n;
            const int xx = (int)idx % n;
            const float fs = (float)stride;
            const float cx = (xx + 0.5f) * fs + r0 * fs;
            const float cy = (yy + 0.5f) * fs + r1 * fs;
            const float w2 = 0.5f * expf(r2) * fs;
            const float h2 = 0.5f * expf(r3) * fs;
            orow[0] = keep * (cx - w2);
            orow[1] = keep * (cy - h2);
            orow[2] = keep * (cx + w2);
            orow[3] = keep * (cy + h2);
        }
    }
}

extern "C" void kernel_launch(void* const* d_in, const int* in_sizes, int n_in,
                              void* d_out, int out_size, void* d_ws, size_t ws_size,
                              hipStream_t stream) {
    (void)in_sizes; (void)n_in; (void)out_size; (void)ws_size;
    unsigned int* ctr = (unsigned int*)d_ws;                 // 96 * 4 B
    uint2* cand = (uint2*)((char*)d_ws + 512);               // 96*4*50*8 = 153600 B

    Args a;
    for (int l = 0; l < 3; ++l) {
        a.conf[l] = (const float*)d_in[l * 6 + 0];
        a.obj[l]  = (const float*)d_in[l * 6 + 1];
        a.act[l]  = (const float*)d_in[l * 6 + 2];
        a.rel[l]  = (const float*)d_in[l * 6 + 3];
        a.intp[l] = (const float*)d_in[l * 6 + 4];
        a.reg[l]  = (const float*)d_in[l * 6 + 5];
    }
    a.ctr  = ctr;
    a.cand = cand;
    a.out  = (float*)d_out;

    // stream-ordered counter reset: makes every graph replay start from 0
    hipMemsetAsync(ctr, 0, 96 * sizeof(unsigned int), stream);
    hipLaunchKernelGGL(yowo_fused_kernel, dim3(384), dim3(NT), 0, stream, a);
}

// Round 7
// 19.150 us; speedup vs baseline: 4.3837x; 4.3837x over previous
//
#include <hip/hip_runtime.h>
#include <math.h>

#define TOPK 50
#define NCH 225
#define NT 1024
#define NW 16
#define MAXIT 7             // ceil(25600 / 4096)
#define CAP 512
#define NBINS 4096
#define BPT 4               // bins per thread (4096 / 1024)
#define PADC 5              // padded chunk stride (coprime with 32 banks)

// monotone float->uint key: preserves ordering, larger float -> larger key
__device__ __forceinline__ unsigned int f2key(float f) {
    unsigned int u = __float_as_uint(f);
    return (u & 0x80000000u) ? ~u : (u | 0x80000000u);
}
__device__ __forceinline__ float key2f(unsigned int k) {
    unsigned int u = (k & 0x80000000u) ? (k ^ 0x80000000u) : ~k;
    return __uint_as_float(u);
}
__device__ __forceinline__ int pbin(unsigned int bin) {
    return (int)((bin >> 2) * PADC + (bin & 3u));
}

struct ArgsA { const float* conf[3]; uint2* sel; };

struct ArgsB {
    const float* obj[3];
    const float* act[3];
    const float* rel[3];
    const float* intp[3];
    const float* reg[3];
    const uint2* sel;
    float* out;
};

// ---- Kernel A: exact top-50 per (lvl, batch); threshold-probe fast path ----
__global__ __launch_bounds__(NT)
void yowo_select_kernel(ArgsA a) {
    __shared__ unsigned int s_hist[NT * PADC];   // 20 KB
    __shared__ unsigned int s_w[NW];
    __shared__ unsigned int s_woff[NW];
    __shared__ unsigned int s_ck[CAP];
    __shared__ unsigned int s_ci[CAP];
    __shared__ unsigned int s_selKey[TOPK];
    __shared__ unsigned int s_selIdx[TOPK];
    __shared__ unsigned int s_cnt;
    __shared__ unsigned int s_total;
    __shared__ unsigned int s_bin, s_cntGe;
    __shared__ unsigned long long s_wred[NW];
    __shared__ unsigned long long s_prev;

    const int tid  = threadIdx.x;
    const int wid  = tid >> 6;
    const int lane = tid & 63;
    const int lvl  = blockIdx.x >> 5;
    const int b    = blockIdx.x & 31;
    const int M    = (lvl == 0) ? 25600 : (lvl == 1) ? 6400 : 1600;
    // probe thresholds: expected candidate count ~126/89/88 for N(0,1) logits;
    // any miss falls back to the exact histogram path below.
    const float Tf = (lvl == 0) ? 2.58f : (lvl == 1) ? 2.2f : 1.6f;
    const unsigned int Tkey = f2key(Tf);
    const float* confp = a.conf[lvl] + (size_t)b * M;

    // ---- load conf once; keys to registers; count keys > Tkey ----
    uint4 kk[MAXIT];
    int lc = 0;
    #pragma unroll
    for (int it = 0; it < MAXIT; ++it) {
        const int m = tid * 4 + it * (NT * 4);
        if (m < M) {
            float4 c4 = *(const float4*)(confp + m);
            uint4 k4 = make_uint4(f2key(c4.x), f2key(c4.y), f2key(c4.z), f2key(c4.w));
            kk[it] = k4;
            lc += (k4.x > Tkey) + (k4.y > Tkey) + (k4.z > Tkey) + (k4.w > Tkey);
        } else {
            kk[it] = make_uint4(0u, 0u, 0u, 0u);
        }
    }
    // block-wide count
    int c = lc;
    #pragma unroll
    for (int off = 32; off > 0; off >>= 1) c += __shfl_xor(c, off, 64);
    if (lane == 0) s_w[wid] = (unsigned int)c;
    __syncthreads();
    if (tid == 0) {
        unsigned int t = 0u;
        #pragma unroll
        for (int j = 0; j < NW; ++j) t += s_w[j];
        s_total = t;
    }
    __syncthreads();
    const unsigned int total = s_total;

    unsigned int thrU = 0u;
    bool ok;
    if (total >= TOPK && total <= CAP) {
        thrU = Tkey + 1u;            // k > Tkey  <=>  k >= Tkey+1
        ok = true;
    } else {
        // ---- exact fallback: 12-bit histogram select ----
        {
            const int zb = tid * PADC;
            #pragma unroll
            for (int j = 0; j < PADC; ++j) s_hist[zb + j] = 0u;
        }
        __syncthreads();
        #pragma unroll
        for (int it = 0; it < MAXIT; ++it) {
            const int m = tid * 4 + it * (NT * 4);
            if (m < M) {
                const uint4 k4 = kk[it];
                atomicAdd(&s_hist[pbin(k4.x >> 20)], 1u);
                atomicAdd(&s_hist[pbin(k4.y >> 20)], 1u);
                atomicAdd(&s_hist[pbin(k4.z >> 20)], 1u);
                atomicAdd(&s_hist[pbin(k4.w >> 20)], 1u);
            }
        }
        __syncthreads();
        const int pb = tid * PADC;
        unsigned int ct = 0u;
        #pragma unroll
        for (int j = 0; j < BPT; ++j) ct += s_hist[pb + j];
        unsigned int sfx = ct;
        #pragma unroll
        for (int off = 1; off < 64; off <<= 1) {
            unsigned int v = __shfl_down(sfx, off, 64);
            if (lane + off < 64) sfx += v;
        }
        if (lane == 0) s_w[wid] = sfx;
        __syncthreads();
        if (tid < NW) {
            unsigned int o = 0u;
            for (int j = tid + 1; j < NW; ++j) o += s_w[j];
            s_woff[tid] = o;
        }
        __syncthreads();
        const unsigned int S_incl = sfx + s_woff[wid];
        const unsigned int right  = S_incl - ct;
        if (right < TOPK && S_incl >= TOPK) {
            unsigned int cge = right;
            #pragma unroll
            for (int j = BPT - 1; j >= 0; --j) {
                cge += s_hist[pb + j];
                if (cge >= TOPK) {
                    s_bin = (unsigned int)(tid * BPT + j);
                    s_cntGe = cge;
                    break;
                }
            }
        }
        __syncthreads();
        if (s_cntGe <= CAP) { thrU = s_bin << 20; ok = true; }
        else ok = false;
    }

    if (ok) {
        // ---- compact candidates (register-held keys) + rank-sort ----
        __syncthreads();
        if (tid == 0) s_cnt = 0u;
        __syncthreads();
        #pragma unroll
        for (int it = 0; it < MAXIT; ++it) {
            const int m = tid * 4 + it * (NT * 4);
            if (m < M) {
                const uint4 k4 = kk[it];
                #pragma unroll
                for (int j = 0; j < 4; ++j) {
                    const unsigned int k = (j == 0) ? k4.x : (j == 1) ? k4.y
                                         : (j == 2) ? k4.z : k4.w;
                    if (k >= thrU) {
                        unsigned int pos = atomicAdd(&s_cnt, 1u);
                        if (pos < CAP) {
                            s_ck[pos] = k;
                            s_ci[pos] = (unsigned int)(m + j);
                        }
                    }
                }
            }
        }
        __syncthreads();
        const unsigned int cnt = s_cnt;
        if (tid < (int)cnt) {
            const unsigned long long p =
                ((unsigned long long)s_ck[tid] << 32) | (unsigned int)(~s_ci[tid]);
            int rank = 0;
            for (unsigned int j = 0; j < cnt; ++j) {
                const unsigned long long q =
                    ((unsigned long long)s_ck[j] << 32) | (unsigned int)(~s_ci[j]);
                rank += (q > p) ? 1 : 0;
            }
            if (rank < TOPK) { s_selKey[rank] = s_ck[tid]; s_selIdx[rank] = s_ci[tid]; }
        }
        __syncthreads();
    } else {
        // ---- ultra fallback (massive key ties; never expected): 50 max passes ----
        unsigned long long prev = 0xFFFFFFFFFFFFFFFFull;
        for (int i = 0; i < TOPK; ++i) {
            unsigned long long p = 0ull;
            #pragma unroll
            for (int it = 0; it < MAXIT; ++it) {
                const int m = tid * 4 + it * (NT * 4);
                if (m < M) {
                    const uint4 k4 = kk[it];
                    #pragma unroll
                    for (int j = 0; j < 4; ++j) {
                        const unsigned int k = (j == 0) ? k4.x : (j == 1) ? k4.y
                                             : (j == 2) ? k4.z : k4.w;
                        const unsigned long long pk =
                            ((unsigned long long)k << 32) |
                            (unsigned int)(~(unsigned int)(m + j));
                        if (pk < prev && pk > p) p = pk;
                    }
                }
            }
            #pragma unroll
            for (int off = 32; off > 0; off >>= 1) {
                unsigned long long q = __shfl_xor(p, off, 64);
                if (q > p) p = q;
            }
            if (lane == 0) s_wred[wid] = p;
            __syncthreads();
            if (tid == 0) {
                unsigned long long w = s_wred[0];
                #pragma unroll
                for (int j = 1; j < NW; ++j) if (s_wred[j] > w) w = s_wred[j];
                s_prev = w;
                s_selKey[i] = (unsigned int)(w >> 32);
                s_selIdx[i] = ~(unsigned int)w;
            }
            __syncthreads();
            prev = s_prev;
            __syncthreads();
        }
    }

    if (tid < TOPK)
        a.sel[(size_t)blockIdx.x * TOPK + tid] =
            make_uint2(s_selKey[tid], s_selIdx[tid]);
}

// ---- Kernel B: pure gather/epilogue, one row per wave ----
__global__ __launch_bounds__(NT)
void yowo_out_kernel(ArgsB a) {
    __shared__ unsigned int s_k[TOPK];
    __shared__ unsigned int s_i[TOPK];

    const int tid  = threadIdx.x;
    const int wid  = tid >> 6;
    const int lane = tid & 63;
    const int grp  = blockIdx.x >> 2;   // 0..95 = lvl*32 + b
    const int sub  = blockIdx.x & 3;
    const int lvl  = grp >> 5;
    const int b    = grp & 31;

    const int M      = (lvl == 0) ? 25600 : (lvl == 1) ? 6400 : 1600;
    const int stride = 8 << lvl;
    const int n      = 1280 / stride;

    if (tid < TOPK) {
        uint2 e = a.sel[(size_t)grp * TOPK + tid];
        s_k[tid] = e.x;
        s_i[tid] = e.y;
    }
    __syncthreads();

    const int k = sub + 4 * wid;
    if (k < TOPK) {
        const unsigned int idx = s_i[k];
        const float logit = key2f(s_k[k]);
        const float sc   = 1.0f / (1.0f + expf(-logit));
        const float keep = (sc > 0.05f) ? 1.0f : 0.0f;

        float* orow = a.out + ((size_t)b * 150 + (size_t)lvl * TOPK + k) * NCH;
        const size_t rbase = (size_t)b * M + idx;

        // obj softmax over 36 classes (full-wave shuffle sum; lanes>=36 add 0)
        float e = 0.0f;
        if (lane < 36) e = expf(a.obj[lvl][rbase * 36 + lane]);
        float s = e;
        #pragma unroll
        for (int off = 32; off > 0; off >>= 1) s += __shfl_xor(s, off, 64);
        if (lane < 36) orow[6 + lane] = keep * (e / s);

        // act sigmoid (157)
        for (int cix = lane; cix < 157; cix += 64) {
            float x = a.act[lvl][rbase * 157 + cix];
            orow[42 + cix] = keep / (1.0f + expf(-x));
        }
        // rel sigmoid (26)
        if (lane < 26) {
            float x = a.rel[lvl][rbase * 26 + lane];
            orow[199 + lane] = keep / (1.0f + expf(-x));
        }
        // conf, inter, box
        if (lane == 0) {
            orow[4] = keep * sc;
            float xi = a.intp[lvl][rbase];
            orow[5] = keep / (1.0f + expf(-xi));
            const float r0 = a.reg[lvl][rbase * 4 + 0];
            const float r1 = a.reg[lvl][rbase * 4 + 1];
            const float r2 = a.reg[lvl][rbase * 4 + 2];
            const float r3 = a.reg[lvl][rbase * 4 + 3];
            const int yy = (int)idx / n;
            const int xx = (int)idx % n;
            const float fs = (float)stride;
            const float cx = (xx + 0.5f) * fs + r0 * fs;
            const float cy = (yy + 0.5f) * fs + r1 * fs;
            const float w2 = 0.5f * expf(r2) * fs;
            const float h2 = 0.5f * expf(r3) * fs;
            orow[0] = keep * (cx - w2);
            orow[1] = keep * (cy - h2);
            orow[2] = keep * (cx + w2);
            orow[3] = keep * (cy + h2);
        }
    }
}

extern "C" void kernel_launch(void* const* d_in, const int* in_sizes, int n_in,
                              void* d_out, int out_size, void* d_ws, size_t ws_size,
                              hipStream_t stream) {
    (void)in_sizes; (void)n_in; (void)out_size; (void)ws_size;
    uint2* sel = (uint2*)d_ws;            // 96*50*8 = 38400 B

    ArgsA aa;
    ArgsB ab;
    for (int l = 0; l < 3; ++l) {
        aa.conf[l] = (const float*)d_in[l * 6 + 0];
        ab.obj[l]  = (const float*)d_in[l * 6 + 1];
        ab.act[l]  = (const float*)d_in[l * 6 + 2];
        ab.rel[l]  = (const float*)d_in[l * 6 + 3];
        ab.intp[l] = (const float*)d_in[l * 6 + 4];
        ab.reg[l]  = (const float*)d_in[l * 6 + 5];
    }
    aa.sel = sel;
    ab.sel = sel;
    ab.out = (float*)d_out;

    hipLaunchKernelGGL(yowo_select_kernel, dim3(96), dim3(NT), 0, stream, aa);
    hipLaunchKernelGGL(yowo_out_kernel, dim3(384), dim3(NT), 0, stream, ab);
}